// Round 8
// baseline (6380.312 us; speedup 1.0000x reference)
//
#include <hip/hip_runtime.h>

// Problem constants (fixed by the reference)
#define M_ROWS 106496   // 4096*26  (n,v) rows
#define NBATCH 4096
#define VN 26
#define KNUM 3
#define TS 25

typedef unsigned short u16;
typedef __attribute__((ext_vector_type(8))) short v8s;
typedef __attribute__((ext_vector_type(4))) float v4f;

__device__ __forceinline__ u16 f2bf(float f) {
    unsigned u = __float_as_uint(f);
    u += 0x7FFF + ((u >> 16) & 1);   // RNE
    return (u16)(u >> 16);
}
__device__ __forceinline__ float bf2f(u16 h) {
    return __uint_as_float(((unsigned)h) << 16);
}
__device__ __forceinline__ float sigm(float x) {
    return 1.f / (1.f + __expf(-x));
}
__device__ __forceinline__ float tanh_fast(float x) {
    return 2.f / (1.f + __expf(-2.f * x)) - 1.f;
}

// Async global->LDS, 16B per lane. LDS dest must be the wave-uniform base;
// HW adds lane*16. Staging layout stays LINEAR in lane order; the LDS
// swizzle is realized by pre-permuting the per-lane GLOBAL source chunk
// (rule: both-sides-or-neither with global_load_lds).
typedef const __attribute__((address_space(1))) unsigned int* gas_t;
typedef __attribute__((address_space(3))) unsigned int* las_t;
__device__ __forceinline__ void gl16(const void* g, void* l) {
    __builtin_amdgcn_global_load_lds((gas_t)g, (las_t)l, 16, 0, 0);
}

// ---------------------------------------------------------------------------
// Fused conv-gemm + graph mix, TWO batch-n per block (grid 2048).
// R7 post-mortem: 221 us was latency-bound on (1) per-block redundant 384 KB
// weight streaming through 16 single-buffered barrier steps, (2) the mix's
// 78 serial ~200cy aadj row loads. Fixes: 2n/block halves (1) per unit work
// and doubles FMAs per aadj load; explicit even/odd register prefetch of
// padded aadj rows (aadjp, 32-float stride) kills (2)'s exposed latency.
// Output remains BITWISE-identical: per-thread (k,v) order k0,k1,k2 x v0..25,
// same fp32 accumulate, same f2bf points. Rows 52..63 of the M-tile are
// computed and discarded (last block's A over-read lands in hB: harmless).
// LDS: Al 4K + Bst 24K + Yl 39K = 67 KB -> 2 blocks/CU.
// ---------------------------------------------------------------------------
#define LDROW(dst, kk, vv) do {                                             \
    const float4* _p = (const float4*)&aadjp[((kk) * 26 + (vv)) * 32];      \
    *(float4*)&dst[0]  = _p[0]; *(float4*)&dst[4]  = _p[1];                 \
    *(float4*)&dst[8]  = _p[2]; *(float4*)&dst[12] = _p[3];                 \
    *(float4*)&dst[16] = _p[4]; *(float4*)&dst[20] = _p[5];                 \
    *(float4*)&dst[24] = _p[6]; } while (0)

#define MIXV(A, vv, o) do {                                                 \
    float y0 = bf2f(Yl[(vv) * 384 + ((((o) >> 3) ^ ((vv) & 7)) << 3) + ((o) & 7)]); \
    float y1 = bf2f(Yl[((vv) + 26) * 384 + ((((o) >> 3) ^ (((vv) + 26) & 7)) << 3) + ((o) & 7)]); \
    _Pragma("unroll") for (int w = 0; w < 26; ++w) {                        \
        am0[w] += y0 * A[w]; am1[w] += y1 * A[w]; } } while (0)

#define MIXK(kk, oo) do { const int _o = (oo);                              \
    float ae[28], ao[28];                                                   \
    LDROW(ae, kk, 0);                                                       \
    _Pragma("unroll") for (int vv = 0; vv < 26; vv += 2) {                  \
        LDROW(ao, kk, vv + 1);                                              \
        MIXV(ae, vv, _o);                                                   \
        if (vv + 2 < 26) LDROW(ae, kk, vv + 2);                             \
        MIXV(ao, vv + 1, _o);                                               \
    } } while (0)

__global__ __launch_bounds__(256) void conv_mix(
    const u16* __restrict__ hA, const u16* __restrict__ convw,
    const float* __restrict__ convb, const float* __restrict__ aadjp,
    u16* __restrict__ msg)
{
    __shared__ u16 Al[64 * 32];     // 4 KB A tile (52 real rows + 12 junk)
    __shared__ u16 Bst[384 * 32];   // 24 KB weight tile
    __shared__ u16 Yl[52 * 384];    // 39 KB swizzled y panel (one pass)
    const int bn = blockIdx.x, tid = threadIdx.x;
    const int wid = tid >> 6, lane = tid & 63;
    const int ln = lane & 15, q = lane >> 4;
    const int qs8 = (q ^ ((ln >> 1) & 3)) * 8;
    const int wn = wid * 96;                 // 96 of 384 cols per wave
    const int srow = tid >> 2;
    const int spart = (tid & 3) ^ ((srow >> 1) & 3);
    const int c = tid;

    const size_t rbase = (size_t)bn * 52;
    const u16* gA0 = &hA[(rbase + srow) * 256 + spart * 8];
    const u16* gW0 = &convw[(size_t)srow * 256 + spart * 8];

    float am0[26], am1[26];
#pragma unroll
    for (int w = 0; w < 26; ++w) { am0[w] = 0.f; am1[w] = 0.f; }

#pragma unroll
    for (int p = 0; p < 2; ++p) {
        v4f acc[4][6] = {};
        const u16* gW = gW0 + (size_t)p * 384 * 256;
        for (int kt = 0; kt < 8; ++kt) {
            gl16(gA0 + kt * 32, &Al[wid * 512]);
#pragma unroll
            for (int t = 0; t < 6; ++t)
                gl16(gW + (size_t)t * 64 * 256 + kt * 32,
                     &Bst[t * 2048 + wid * 512]);
            __syncthreads();
            v8s af[4], bf[6];
#pragma unroll
            for (int i = 0; i < 4; ++i)
                af[i] = *(const v8s*)&Al[(i * 16 + ln) * 32 + qs8];
#pragma unroll
            for (int j = 0; j < 6; ++j)
                bf[j] = *(const v8s*)&Bst[(wn + j * 16 + ln) * 32 + qs8];
#pragma unroll
            for (int i = 0; i < 4; ++i)
#pragma unroll
                for (int j = 0; j < 6; ++j)
                    acc[i][j] = __builtin_amdgcn_mfma_f32_16x16x32_bf16(
                        af[i], bf[j], acc[i][j], 0, 0, 0);
            __syncthreads();
        }
        // epilogue: rows < 52 -> swizzled Yl (same f2bf point as old ybuf)
#pragma unroll
        for (int i = 0; i < 4; ++i)
#pragma unroll
            for (int j = 0; j < 6; ++j) {
                int o = wn + j * 16 + ln;
                float cb = convb[p * 384 + o];
#pragma unroll
                for (int r = 0; r < 4; ++r) {
                    int row = i * 16 + q * 4 + r;
                    if (row < 52) {
                        float v = acc[i][j][r] + cb;
                        int ch = (o >> 3) ^ (row & 7);
                        Yl[row * 384 + ch * 8 + (o & 7)] = f2bf(v);
                    }
                }
            }
        __syncthreads();
        // mix for the k-slices this pass completed (wave-uniform branches):
        // pass0 cols 0..383 = k0(all c) + k1(c<128); pass1 = k1(c>=128)+k2.
        // Per-thread order stays k0,k1,k2 with v 0..25 -> bitwise-identical.
        if (p == 0) {
            MIXK(0, c);
            if (c < 128) MIXK(1, 256 + c);
        } else {
            if (c >= 128) MIXK(1, c - 128);
            MIXK(2, 128 + c);
        }
        // next pass's kt-loop barriers order all threads before Yl rewrite
    }

    // msg rows: n0 = bn*2 -> rows rbase+v ; n1 -> rows rbase+26+v
#pragma unroll
    for (int v = 0; v < 26; ++v)
        msg[(rbase + v) * 256 + c] = f2bf(am0[v]);
#pragma unroll
    for (int v = 0; v < 26; ++v)
        msg[(rbase + 26 + v) * 256 + c] = f2bf(am1[v]);
}

// ---------------------------------------------------------------------------
// Fused MLP head: one kernel for W1 -> W2 -> W3 -> finisher (R5-exact,
// measured good). BM=64 rows/block, grid 1664. hd/hd2 never touch HBM.
// ---------------------------------------------------------------------------
__global__ __launch_bounds__(256) void mlp_head(
    const u16* __restrict__ A, const u16* __restrict__ w1,
    const float* __restrict__ b1, const u16* __restrict__ w2,
    const float* __restrict__ b2, const float* __restrict__ w3,
    const float* __restrict__ b3, const float* __restrict__ p1,
    const float* __restrict__ p2, float* __restrict__ pnew,
    u16* __restrict__ xpad, float* __restrict__ out, int s)
{
    __shared__ u16 Ast[2][64 * 32];     // 2 x 4 KB
    __shared__ u16 Bst[2][256 * 32];    // 2 x 16 KB
    __shared__ u16 hdl[64 * 256];       // 32 KB, chunk-XOR swizzled
    __shared__ float resl[2][64][3];    // 1.5 KB
    const int m0 = blockIdx.x * 64;
    const int tid = threadIdx.x;
    const int wid = tid >> 6, lane = tid & 63;
    const int ln = lane & 15, q = lane >> 4;
    const int qs8 = (q ^ ((ln >> 1) & 3)) * 8;
    const int wm = (wid >> 1) * 32;     // 0 / 32
    const int wn = (wid & 1) * 128;     // 0 / 128
    const int wnh = wid & 1;
    const int srow = tid >> 2;
    const int spart = (tid & 3) ^ ((srow >> 1) & 3);

    const u16* gA0 = &A[(size_t)(m0 + srow) * 256 + spart * 8];
    const u16* gW1 = &w1[(size_t)srow * 256 + spart * 8];
    const u16* gW2 = &w2[(size_t)srow * 256 + spart * 8];

#define STGA(b, kk) gl16(gA0 + (kk) * 32, &Ast[b][wid * 512])
#define STGB(b, kk, W) do {                                                 \
        gl16(W + (kk) * 32,             &Bst[b][wid * 512]);                \
        gl16(W + 64 * 256 + (kk) * 32,  &Bst[b][2048 + wid * 512]);         \
        gl16(W + 128 * 256 + (kk) * 32, &Bst[b][4096 + wid * 512]);         \
        gl16(W + 192 * 256 + (kk) * 32, &Bst[b][6144 + wid * 512]);         \
    } while (0)

    // ---- phase 1: acc = A @ W1^T ----
    v4f acc[2][8] = {};
    STGA(0, 0); STGB(0, 0, gW1);
    __syncthreads();
    for (int kt = 0; kt < 8; ++kt) {
        const int cb = kt & 1, nb = cb ^ 1;
        if (kt < 7) { STGA(nb, kt + 1); STGB(nb, kt + 1, gW1); }
        else        { STGB(nb, 0, gW2); }
        v8s af[2], bf[8];
#pragma unroll
        for (int i = 0; i < 2; ++i)
            af[i] = *(const v8s*)&Ast[cb][(wm + i * 16 + ln) * 32 + qs8];
#pragma unroll
        for (int j = 0; j < 8; ++j)
            bf[j] = *(const v8s*)&Bst[cb][(wn + j * 16 + ln) * 32 + qs8];
#pragma unroll
        for (int i = 0; i < 2; ++i)
#pragma unroll
            for (int j = 0; j < 8; ++j)
                acc[i][j] = __builtin_amdgcn_mfma_f32_16x16x32_bf16(
                    af[i], bf[j], acc[i][j], 0, 0, 0);
        __syncthreads();
    }

    // ---- epilogue 1: hd -> swizzled LDS ----
#pragma unroll
    for (int i = 0; i < 2; ++i)
#pragma unroll
        for (int j = 0; j < 8; ++j) {
            int col = wn + j * 16 + ln;
            float bb = b1[col];
#pragma unroll
            for (int r = 0; r < 4; ++r) {
                int row = wm + i * 16 + q * 4 + r;
                float v = acc[i][j][r] + bb;
                v = v > 0.f ? v : 0.1f * v;
                int ch = (col >> 3) ^ (row & 15);
                hdl[row * 256 + ch * 8 + (col & 7)] = f2bf(v);
            }
        }
    __syncthreads();

    // ---- phase 2: acc2 = hd @ W2^T ----
    v4f acc2[2][8] = {};
    for (int kt = 0; kt < 8; ++kt) {
        const int cb = kt & 1, nb = cb ^ 1;
        if (kt < 7) STGB(nb, kt + 1, gW2);
        v8s af[2], bf[8];
#pragma unroll
        for (int i = 0; i < 2; ++i) {
            int row = wm + i * 16 + ln;
            int ch = (kt * 4 + q) ^ (row & 15);
            af[i] = *(const v8s*)&hdl[row * 256 + ch * 8];
        }
#pragma unroll
        for (int j = 0; j < 8; ++j)
            bf[j] = *(const v8s*)&Bst[cb][(wn + j * 16 + ln) * 32 + qs8];
#pragma unroll
        for (int i = 0; i < 2; ++i)
#pragma unroll
            for (int j = 0; j < 8; ++j)
                acc2[i][j] = __builtin_amdgcn_mfma_f32_16x16x32_bf16(
                    af[i], bf[j], acc2[i][j], 0, 0, 0);
        __syncthreads();
    }
#undef STGA
#undef STGB

    // ---- epilogue 2: leaky + W3 partial dot + butterfly over ln ----
    float part[3][2][4] = {};
#pragma unroll
    for (int j = 0; j < 8; ++j) {
        int col = wn + j * 16 + ln;
        float bb = b2[col];
        float w30 = w3[col], w31 = w3[256 + col], w32 = w3[512 + col];
#pragma unroll
        for (int i = 0; i < 2; ++i)
#pragma unroll
            for (int r = 0; r < 4; ++r) {
                float v = acc2[i][j][r] + bb;
                v = v > 0.f ? v : 0.1f * v;
                part[0][i][r] += v * w30;
                part[1][i][r] += v * w31;
                part[2][i][r] += v * w32;
            }
    }
#pragma unroll
    for (int off = 1; off < 16; off <<= 1)
#pragma unroll
        for (int t = 0; t < 3; ++t)
#pragma unroll
            for (int i = 0; i < 2; ++i)
#pragma unroll
                for (int r = 0; r < 4; ++r)
                    part[t][i][r] += __shfl_xor(part[t][i][r], off, 16);
    if (ln == 0) {
#pragma unroll
        for (int i = 0; i < 2; ++i)
#pragma unroll
            for (int r = 0; r < 4; ++r) {
                int row = wm + i * 16 + q * 4 + r;
#pragma unroll
                for (int t = 0; t < 3; ++t)
                    resl[wnh][row][t] = part[t][i][r];
            }
    }
    __syncthreads();

    // ---- in-block finisher (64 threads, one row each) ----
    if (tid < 64) {
        int m = m0 + tid;
        float s0 = resl[0][tid][0] + resl[1][tid][0];
        float s1 = resl[0][tid][1] + resl[1][tid][1];
        float s2 = resl[0][tid][2] + resl[1][tid][2];
        float a0 = p1[m * 3 + 0], a1 = p1[m * 3 + 1], a2 = p1[m * 3 + 2];
        float c0 = p2[m * 3 + 0], c1 = p2[m * 3 + 1], c2 = p2[m * 3 + 2];
        float o0 = a0 + s0 + b3[0];
        float o1 = a1 + s1 + b3[1];
        float o2 = a2 + s2 + b3[2];
        size_t ob = ((size_t)m * TS + s) * 3;
        out[ob + 0] = o0; out[ob + 1] = o1; out[ob + 2] = o2;
        pnew[m * 3 + 0] = o0; pnew[m * 3 + 1] = o1; pnew[m * 3 + 2] = o2;
        unsigned t[32];
#pragma unroll
        for (int i = 0; i < 32; ++i) t[i] = 0;
        t[0] = f2bf(o0); t[1] = f2bf(o1); t[2] = f2bf(o2);
        t[3] = f2bf(a0 - c0); t[4] = f2bf(a1 - c1); t[5] = f2bf(a2 - c2);
        t[6] = f2bf(o0 - 2.f * a0 + c0);
        t[7] = f2bf(o1 - 2.f * a1 + c1);
        t[8] = f2bf(o2 - 2.f * a2 + c2);
        t[9] = f2bf(1.f);
        uint4* dst = (uint4*)&xpad[(size_t)m * 32];
#pragma unroll
        for (int wq = 0; wq < 4; ++wq) {
            uint4 u;
            u.x = t[wq * 8 + 0] | (t[wq * 8 + 1] << 16);
            u.y = t[wq * 8 + 2] | (t[wq * 8 + 3] << 16);
            u.z = t[wq * 8 + 4] | (t[wq * 8 + 5] << 16);
            u.w = t[wq * 8 + 6] | (t[wq * 8 + 7] << 16);
            dst[wq] = u;
        }
    }
}

// ---------------------------------------------------------------------------
// Fused GRU, K=288: cols 0..255 = msg (Wh*), 256..287 = xpad (x-proj + bias).
// BYTE-EXACT R3 structure (115.5 us @ 20.4% occupancy, VGPR 116): rolled kt
// loop (NO unroll — R2's unroll cost 140 VGPR / 11% occ / 196 us), single
// LDS buffer, two barriers per K-step, constant-folded XOR swizzle.
// grid = (832, 4). DO NOT TOUCH.
// ---------------------------------------------------------------------------
__global__ __launch_bounds__(256) void gru_fused(
    const u16* __restrict__ Am, const u16* __restrict__ xpad,
    const u16* __restrict__ hprev, u16* __restrict__ hout,
    const u16* __restrict__ wfull, const u16* __restrict__ wxn)
{
    __shared__ u16 Al[128 * 32];   // 8 KB
    __shared__ u16 Bl[192 * 32];   // 12 KB
    __shared__ u16 Xl[64 * 32];    // 4 KB
    const int m0 = blockIdx.x * 128;
    const int n0 = blockIdx.y * 64;
    const int tid = threadIdx.x;
    const int wid = tid >> 6, lane = tid & 63;
    const int ln = lane & 15, q = lane >> 4;
    const int qs8 = (q ^ ((ln >> 1) & 3)) * 8;
    const int wm = (wid >> 1) * 64, wn = (wid & 1) * 32;
    const int srow = tid >> 2;
    const int spart = (tid & 3) ^ ((srow >> 1) & 3);

    // wxn tile (64 rows of this block's n0 slice), needed only at kt==8
    gl16(&wxn[(size_t)(n0 + srow) * 32 + spart * 8], &Xl[(wid * 64) * 8]);

    v4f accr[4][2] = {}, accz[4][2] = {}, acch[4][2] = {}, accn[4][2] = {};

    for (int kt = 0; kt < 9; ++kt) {
#pragma unroll
        for (int p = 0; p < 2; ++p) {
            const u16* ga = (kt < 8)
                ? &Am[(size_t)(m0 + p * 64 + srow) * 256 + kt * 32 + spart * 8]
                : &xpad[(size_t)(m0 + p * 64 + srow) * 32 + spart * 8];
            gl16(ga, &Al[(p * 256 + wid * 64) * 8]);
        }
#pragma unroll
        for (int p = 0; p < 3; ++p)
            gl16(&wfull[(size_t)(p * 256 + n0 + srow) * 288 + kt * 32 + spart * 8],
                 &Bl[(p * 256 + wid * 64) * 8]);
        __syncthreads();

        v8s af[4];
#pragma unroll
        for (int i = 0; i < 4; ++i)
            af[i] = *(const v8s*)&Al[(wm + i * 16 + ln) * 32 + qs8];
        v8s bfr[3][2];
#pragma unroll
        for (int g = 0; g < 3; ++g)
#pragma unroll
            for (int j = 0; j < 2; ++j)
                bfr[g][j] = *(const v8s*)&Bl[(g * 64 + wn + j * 16 + ln) * 32 + qs8];
#pragma unroll
        for (int i = 0; i < 4; ++i)
#pragma unroll
            for (int j = 0; j < 2; ++j) {
                accr[i][j] = __builtin_amdgcn_mfma_f32_16x16x32_bf16(af[i], bfr[0][j], accr[i][j], 0, 0, 0);
                accz[i][j] = __builtin_amdgcn_mfma_f32_16x16x32_bf16(af[i], bfr[1][j], accz[i][j], 0, 0, 0);
                acch[i][j] = __builtin_amdgcn_mfma_f32_16x16x32_bf16(af[i], bfr[2][j], acch[i][j], 0, 0, 0);
            }
        if (kt == 8) {
            v8s bfn[2];
#pragma unroll
            for (int j = 0; j < 2; ++j)
                bfn[j] = *(const v8s*)&Xl[(wn + j * 16 + ln) * 32 + qs8];
#pragma unroll
            for (int i = 0; i < 4; ++i)
#pragma unroll
                for (int j = 0; j < 2; ++j)
                    accn[i][j] = __builtin_amdgcn_mfma_f32_16x16x32_bf16(af[i], bfn[j], accn[i][j], 0, 0, 0);
        }
        __syncthreads();
    }

#pragma unroll
    for (int i = 0; i < 4; ++i)
#pragma unroll
        for (int j = 0; j < 2; ++j) {
            int gc = n0 + wn + j * 16 + ln;
#pragma unroll
            for (int r = 0; r < 4; ++r) {
                int gr = m0 + wm + i * 16 + q * 4 + r;
                float rg = sigm(accr[i][j][r]);
                float zg = sigm(accz[i][j][r]);
                float nn = tanh_fast(accn[i][j][r] + rg * acch[i][j][r]);
                float hp = bf2f(hprev[(size_t)gr * 256 + gc]);
                hout[(size_t)gr * 256 + gc] = f2bf((1.f - zg) * nn + zg * hp);
            }
        }
}

// ---------------------------------------------------------------------------
// Step-0 xpad from the three input frames.
// ---------------------------------------------------------------------------
__global__ __launch_bounds__(256) void init_xpad(
    const float* __restrict__ x0, const float* __restrict__ xp,
    const float* __restrict__ xp2, u16* __restrict__ xpad)
{
    int m = blockIdx.x * 256 + threadIdx.x;
    float a0 = x0[m * 3 + 0], a1 = x0[m * 3 + 1], a2 = x0[m * 3 + 2];
    float b0 = xp[m * 3 + 0], b1 = xp[m * 3 + 1], b2 = xp[m * 3 + 2];
    float c0 = xp2[m * 3 + 0], c1 = xp2[m * 3 + 1], c2 = xp2[m * 3 + 2];
    unsigned t[32];
#pragma unroll
    for (int i = 0; i < 32; ++i) t[i] = 0;
    t[0] = f2bf(a0); t[1] = f2bf(a1); t[2] = f2bf(a2);
    t[3] = f2bf(b0 - c0); t[4] = f2bf(b1 - c1); t[5] = f2bf(b2 - c2);
    t[6] = f2bf(a0 - 2.f * b0 + c0);
    t[7] = f2bf(a1 - 2.f * b1 + c1);
    t[8] = f2bf(a2 - 2.f * b2 + c2);
    t[9] = f2bf(1.f);
    uint4* dst = (uint4*)&xpad[(size_t)m * 32];
#pragma unroll
    for (int wq = 0; wq < 4; ++wq) {
        uint4 u;
        u.x = t[wq * 8 + 0] | (t[wq * 8 + 1] << 16);
        u.y = t[wq * 8 + 2] | (t[wq * 8 + 3] << 16);
        u.z = t[wq * 8 + 4] | (t[wq * 8 + 5] << 16);
        u.w = t[wq * 8 + 6] | (t[wq * 8 + 7] << 16);
        dst[wq] = u;
    }
}

// ---------------------------------------------------------------------------
// hidden [N,C,V] fp32 -> h[(n,v),c] bf16.
// ---------------------------------------------------------------------------
__global__ __launch_bounds__(256) void transpose_h(
    const float* __restrict__ hidden, u16* __restrict__ hA)
{
    __shared__ float hl[256 * VN];
    const int n = blockIdx.x, tid = threadIdx.x;
    const uint4* src = (const uint4*)(hidden + (size_t)n * 256 * VN);
    for (int idx = tid; idx < 256 * VN / 4; idx += 256)
        ((uint4*)hl)[idx] = src[idx];
    __syncthreads();
    size_t base = (size_t)n * VN * 256;
    for (int idx = tid; idx < VN * 256; idx += 256) {
        int v = idx >> 8, c = idx & 255;
        hA[base + idx] = f2bf(hl[c * VN + v]);
    }
}

// ---------------------------------------------------------------------------
// Weight packing (once per call).
// wfull[768,288]: row g*256+c -> cols 0..255 = Wh_g[c,:],
//   256..264 = x-weights (g<2), 265 = bias (g<2), rest 0.
// wxn[256,32]:   row c -> 0..8 = Win[c,:], 9 = b_in[c], rest 0.
// aadjp[78,32]:  row k*26+v -> cols 0..25 = A*emul+eadd row, rest 0.
// ---------------------------------------------------------------------------
__global__ __launch_bounds__(256) void pack_weights(
    const float* __restrict__ Whr, const float* __restrict__ Whi,
    const float* __restrict__ Whh, const float* __restrict__ convw_f,
    const float* __restrict__ W1f, const float* __restrict__ W2f,
    const float* __restrict__ Af, const float* __restrict__ emul,
    const float* __restrict__ eadd, const float* __restrict__ Wir,
    const float* __restrict__ Wii, const float* __restrict__ Win,
    const float* __restrict__ bir, const float* __restrict__ bii,
    const float* __restrict__ b_in, const float* __restrict__ convb_f,
    const float* __restrict__ b1f, const float* __restrict__ b2f,
    const float* __restrict__ W3f, const float* __restrict__ b3f,
    u16* __restrict__ wfull, u16* __restrict__ wxn, u16* __restrict__ convw,
    u16* __restrict__ w1, u16* __restrict__ w2, float* __restrict__ aadjp,
    float* __restrict__ convb, float* __restrict__ b1, float* __restrict__ b2,
    float* __restrict__ w3, float* __restrict__ b3)
{
    int gid = blockIdx.x * 256 + threadIdx.x;
    int stride = gridDim.x * 256;
    for (int i = gid; i < 768 * 288; i += stride) {
        int row = i / 288, col = i - row * 288;
        int g = row >> 8, c = row & 255;
        float v = 0.f;
        if (col < 256)
            v = (g == 0 ? Whr : (g == 1 ? Whi : Whh))[c * 256 + col];
        else if (col < 265) {
            int tcol = col - 256;
            v = (g == 0 ? Wir[c * 9 + tcol] : (g == 1 ? Wii[c * 9 + tcol] : 0.f));
        } else if (col == 265)
            v = (g == 0 ? bir[c] : (g == 1 ? bii[c] : 0.f));
        wfull[i] = f2bf(v);
    }
    for (int i = gid; i < 256 * 32; i += stride) {
        int c = i >> 5, col = i & 31;
        float v = 0.f;
        if (col < 9) v = Win[c * 9 + col];
        else if (col == 9) v = b_in[c];
        wxn[i] = f2bf(v);
    }
    for (int i = gid; i < 65536; i += stride) {
        w1[i] = f2bf(W1f[i]);
        w2[i] = f2bf(W2f[i]);
    }
    for (int i = gid; i < 196608; i += stride) convw[i] = f2bf(convw_f[i]);
    for (int i = gid; i < 78 * 32; i += stride) {
        int row = i >> 5, w = i & 31;
        aadjp[i] = (w < 26)
            ? (Af[row * 26 + w] * emul[row * 26 + w] + eadd[row * 26 + w])
            : 0.f;
    }
    for (int i = gid; i < 256; i += stride) { b1[i] = b1f[i]; b2[i] = b2f[i]; }
    for (int i = gid; i < 768; i += stride) { convb[i] = convb_f[i]; w3[i] = W3f[i]; }
    if (gid < 3) b3[gid] = b3f[gid];
}

// ---------------------------------------------------------------------------
extern "C" void kernel_launch(void* const* d_in, const int* in_sizes, int n_in,
                              void* d_out, int out_size, void* d_ws, size_t ws_size,
                              hipStream_t stream)
{
    const float* inputs   = (const float*)d_in[0];
    const float* inputs_p = (const float*)d_in[1];
    const float* inputs_p2= (const float*)d_in[2];
    const float* hidden   = (const float*)d_in[3];
    const float* Af       = (const float*)d_in[4];
    const float* emul     = (const float*)d_in[5];
    const float* eadd     = (const float*)d_in[6];
    const float* conv_w   = (const float*)d_in[7];
    const float* conv_b   = (const float*)d_in[8];
    const float* Wir      = (const float*)d_in[9];
    const float* bir      = (const float*)d_in[10];
    const float* Wii      = (const float*)d_in[11];
    const float* bii      = (const float*)d_in[12];
    const float* Win      = (const float*)d_in[13];
    const float* b_in     = (const float*)d_in[14];
    const float* Whr      = (const float*)d_in[15];
    const float* Whi      = (const float*)d_in[16];
    const float* Whh      = (const float*)d_in[17];
    const float* W1f      = (const float*)d_in[18];
    const float* b1f      = (const float*)d_in[19];
    const float* W2f      = (const float*)d_in[20];
    const float* b2f      = (const float*)d_in[21];
    const float* W3f      = (const float*)d_in[22];
    const float* b3f      = (const float*)d_in[23];
    float* out = (float*)d_out;

    const size_t M = M_ROWS;
    char* ws = (char*)d_ws;
    size_t off = 0;
    auto alloc = [&](size_t bytes) -> void* {
        void* p = ws + off;
        off = (off + bytes + 255) & ~(size_t)255;
        return p;
    };
    // R3/R5-exact allocation order (gru's measured environment). ybuf unused
    // but kept so every later buffer keeps its address; aadjp appended last.
    u16* hA    = (u16*)alloc(M * 256 * 2);
    u16* hB    = (u16*)alloc(M * 256 * 2);
    u16* msg   = (u16*)alloc(M * 256 * 2);
    u16* ybuf  = (u16*)alloc(M * 768 * 2);
    u16* xpad  = (u16*)alloc(M * 32 * 2);
    float* pa  = (float*)alloc(M * 3 * 4);
    float* pb  = (float*)alloc(M * 3 * 4);
    float* pc  = (float*)alloc(M * 3 * 4);
    u16* wfull = (u16*)alloc(768 * 288 * 2);
    u16* wxn   = (u16*)alloc(256 * 32 * 2);
    u16* convw = (u16*)alloc(196608 * 2);
    u16* w1    = (u16*)alloc(65536 * 2);
    u16* w2    = (u16*)alloc(65536 * 2);
    float* aadj  = (float*)alloc(KNUM * VN * VN * 4);
    float* convb = (float*)alloc(768 * 4);
    float* b1    = (float*)alloc(256 * 4);
    float* b2    = (float*)alloc(256 * 4);
    float* w3    = (float*)alloc(768 * 4);
    float* b3    = (float*)alloc(16);
    float* aadjp = (float*)alloc(78 * 32 * 4);
    (void)ybuf; (void)aadj;
    if (off > ws_size) return;

    pack_weights<<<512, 256, 0, stream>>>(
        Whr, Whi, Whh, conv_w, W1f, W2f, Af, emul, eadd, Wir, Wii, Win,
        bir, bii, b_in, conv_b, b1f, b2f, W3f, b3f,
        wfull, wxn, convw, w1, w2, aadjp, convb, b1, b2, w3, b3);
    transpose_h<<<NBATCH, 256, 0, stream>>>(hidden, hA);
    init_xpad<<<M_ROWS / 256, 256, 0, stream>>>(inputs, inputs_p, inputs_p2, xpad);
    hipMemcpyAsync(pa, inputs,    M * 3 * 4, hipMemcpyDeviceToDevice, stream);
    hipMemcpyAsync(pb, inputs_p,  M * 3 * 4, hipMemcpyDeviceToDevice, stream);
    hipMemcpyAsync(pc, inputs_p2, M * 3 * 4, hipMemcpyDeviceToDevice, stream);

    u16* hcur = hA;  u16* hnext = hB;
    float* P1 = pa;  float* P2 = pb;  float* P3 = pc;
    const int MB = M_ROWS / 128;  // 832

    for (int s = 0; s < TS; ++s) {
        const u16* m_ptr;
        if (s < 10) {
            // conv gemm + graph mix fused, 2 n per block; y stays in LDS
            conv_mix<<<NBATCH / 2, 256, 0, stream>>>(hcur, convw, convb,
                                                     aadjp, msg);
            m_ptr = msg;
        } else {
            m_ptr = hcur;
        }
        gru_fused<<<dim3(MB, 4), 256, 0, stream>>>(m_ptr, xpad, hcur, hnext,
                                                   wfull, wxn);
        // W1+W2+W3+finisher fused: hd/hd2 never touch HBM
        mlp_head<<<M_ROWS / 64, 256, 0, stream>>>(hnext, w1, b1, w2, b2, w3, b3,
                                                  P1, P2, P3, xpad, out, s);
        float* t = P3; P3 = P2; P2 = P1; P1 = t;
        u16* ht = hcur; hcur = hnext; hnext = ht;
    }
}

// Round 9
// 5957.959 us; speedup vs baseline: 1.0709x; 1.0709x over previous
//
#include <hip/hip_runtime.h>

// Problem constants (fixed by the reference)
#define M_ROWS 106496   // 4096*26  (n,v) rows
#define NBATCH 4096
#define VN 26
#define KNUM 3
#define TS 25

typedef unsigned short u16;
typedef __attribute__((ext_vector_type(8))) short v8s;
typedef __attribute__((ext_vector_type(4))) float v4f;

__device__ __forceinline__ u16 f2bf(float f) {
    unsigned u = __float_as_uint(f);
    u += 0x7FFF + ((u >> 16) & 1);   // RNE
    return (u16)(u >> 16);
}
__device__ __forceinline__ float bf2f(u16 h) {
    return __uint_as_float(((unsigned)h) << 16);
}
__device__ __forceinline__ float sigm(float x) {
    return 1.f / (1.f + __expf(-x));
}
__device__ __forceinline__ float tanh_fast(float x) {
    return 2.f / (1.f + __expf(-2.f * x)) - 1.f;
}

// Async global->LDS, 16B per lane. LDS dest must be the wave-uniform base;
// HW adds lane*16. Staging layout stays LINEAR in lane order; the LDS
// swizzle is realized by pre-permuting the per-lane GLOBAL source chunk
// (rule: both-sides-or-neither with global_load_lds).
typedef const __attribute__((address_space(1))) unsigned int* gas_t;
typedef __attribute__((address_space(3))) unsigned int* las_t;
__device__ __forceinline__ void gl16(const void* g, void* l) {
    __builtin_amdgcn_global_load_lds((gas_t)g, (las_t)l, 16, 0, 0);
}

// ---------------------------------------------------------------------------
// Fused conv-gemm + graph mix, one block per batch n. R7-EXACT revert
// (measured 221 us, VGPR 88, occ 22%). R8's 2n+register-prefetch variant
// pushed VGPR to 200 (+96 AGPR > 256 unified) -> 1 wave/SIMD -> 250 us.
// Ledger: R6 flat-H 222us/6.3M conflicts; R7 tiled-H 221us/0.5M conflicts;
// R8 regression. conv_mix's residual stall source is NOT LDS conflicts and
// NOT the aadj scalar-load chain (both fixed with zero time delta) — do not
// edit further without new counter evidence (SQ_WAIT breakdown).
// Output BITWISE-identical to the original gemm_nt<0>+graph_mix pair.
// LDS: Hl 16K + Yl 39K + Bst 24K = 79 KB -> 2 blocks/CU.
// ---------------------------------------------------------------------------
__global__ __launch_bounds__(256) void conv_mix(
    const u16* __restrict__ h, const u16* __restrict__ convw,
    const float* __restrict__ convb, const float* __restrict__ aadj,
    u16* __restrict__ msg)
{
    __shared__ u16 Hl[8 * 32 * 32];  // 16 KB: [kt][row][chunk-swizzled 32]
    __shared__ u16 Yl[26 * 768];     // 39 KB, chunk ^ (row&7) swizzled
    __shared__ u16 Bst[384 * 32];    // 24 KB weight tile
    const int n = blockIdx.x, tid = threadIdx.x;
    const int wid = tid >> 6, lane = tid & 63;
    const int ln = lane & 15, q = lane >> 4;
    const int qs8 = (q ^ ((ln >> 1) & 3)) * 8;
    const int wn = wid * 96;                 // 96 of 384 cols per wave
    const int srow = tid >> 2;
    const int spart = (tid & 3) ^ ((srow >> 1) & 3);

    // stage H tiled+swizzled via plain ds-writes; zero-pad rows 26..31
    for (int idx = tid; idx < 26 * 32; idx += 256) {
        int row = idx >> 5, g = idx & 31;            // g: global 8-col chunk
        uint4 v = *(const uint4*)&h[((size_t)n * 26 + row) * 256 + g * 8];
        int kt = g >> 2;                             // 32-col K-tile
        int gs = (g & 3) ^ ((row >> 1) & 3);         // swizzled chunk in tile
        *(uint4*)&Hl[kt * 1024 + row * 32 + gs * 8] = v;
    }
    {
        uint4 z = {0, 0, 0, 0};
        for (int idx = tid; idx < 6 * 32; idx += 256) {
            int row = 26 + (idx >> 5), g = idx & 31;
            *(uint4*)&Hl[(g >> 2) * 1024 + row * 32 + (g & 3) * 8] = z;
        }
    }

    const u16* gW0 = &convw[(size_t)srow * 256 + spart * 8];
    for (int p = 0; p < 2; ++p) {
        v4f acc[2][6] = {};
        const u16* gW = gW0 + (size_t)p * 384 * 256;
        for (int kt = 0; kt < 8; ++kt) {
#pragma unroll
            for (int t = 0; t < 6; ++t)
                gl16(gW + (size_t)t * 64 * 256 + kt * 32,
                     &Bst[t * 2048 + wid * 512]);
            __syncthreads();
            v8s af[2], bf[6];
#pragma unroll
            for (int i = 0; i < 2; ++i)
                af[i] = *(const v8s*)&Hl[kt * 1024 + (i * 16 + ln) * 32 + qs8];
#pragma unroll
            for (int j = 0; j < 6; ++j)
                bf[j] = *(const v8s*)&Bst[(wn + j * 16 + ln) * 32 + qs8];
#pragma unroll
            for (int i = 0; i < 2; ++i)
#pragma unroll
                for (int j = 0; j < 6; ++j)
                    acc[i][j] = __builtin_amdgcn_mfma_f32_16x16x32_bf16(
                        af[i], bf[j], acc[i][j], 0, 0, 0);
            __syncthreads();
        }
        // epilogue: y rows < 26 -> swizzled Yl (bf16, same rounding point
        // as the old ybuf store)
#pragma unroll
        for (int i = 0; i < 2; ++i)
#pragma unroll
            for (int j = 0; j < 6; ++j) {
                int o = p * 384 + wn + j * 16 + ln;
                float cb = convb[o];
#pragma unroll
                for (int r = 0; r < 4; ++r) {
                    int row = i * 16 + q * 4 + r;
                    if (row < 26) {
                        float v = acc[i][j][r] + cb;
                        int ch = (o >> 3) ^ (row & 7);
                        Yl[row * 768 + ch * 8 + (o & 7)] = f2bf(v);
                    }
                }
            }
    }
    __syncthreads();

    // graph mix: identical loop order / arithmetic to the original graph_mix;
    // aadj read from global (uniform addr -> scalar loads, L2-resident).
    const int c = tid;
    float accm[VN];
#pragma unroll
    for (int w = 0; w < VN; ++w) accm[w] = 0.f;
    for (int k = 0; k < KNUM; ++k)
        for (int v = 0; v < VN; ++v) {
            int o = k * 256 + c;
            float yv = bf2f(Yl[v * 768 + ((o >> 3) ^ (v & 7)) * 8 + (o & 7)]);
            const float* ap = &aadj[(k * VN + v) * VN];
#pragma unroll
            for (int w = 0; w < VN; ++w) accm[w] += yv * ap[w];
        }
    size_t base = (size_t)n * VN * 256;
#pragma unroll
    for (int w = 0; w < VN; ++w) msg[base + w * 256 + c] = f2bf(accm[w]);
}

// ---------------------------------------------------------------------------
// Fused MLP head: one kernel for W1 -> W2 -> W3 -> finisher (R5-exact,
// measured good). BM=64 rows/block, grid 1664. hd/hd2 never touch HBM.
// ---------------------------------------------------------------------------
__global__ __launch_bounds__(256) void mlp_head(
    const u16* __restrict__ A, const u16* __restrict__ w1,
    const float* __restrict__ b1, const u16* __restrict__ w2,
    const float* __restrict__ b2, const float* __restrict__ w3,
    const float* __restrict__ b3, const float* __restrict__ p1,
    const float* __restrict__ p2, float* __restrict__ pnew,
    u16* __restrict__ xpad, float* __restrict__ out, int s)
{
    __shared__ u16 Ast[2][64 * 32];     // 2 x 4 KB
    __shared__ u16 Bst[2][256 * 32];    // 2 x 16 KB
    __shared__ u16 hdl[64 * 256];       // 32 KB, chunk-XOR swizzled
    __shared__ float resl[2][64][3];    // 1.5 KB
    const int m0 = blockIdx.x * 64;
    const int tid = threadIdx.x;
    const int wid = tid >> 6, lane = tid & 63;
    const int ln = lane & 15, q = lane >> 4;
    const int qs8 = (q ^ ((ln >> 1) & 3)) * 8;
    const int wm = (wid >> 1) * 32;     // 0 / 32
    const int wn = (wid & 1) * 128;     // 0 / 128
    const int wnh = wid & 1;
    const int srow = tid >> 2;
    const int spart = (tid & 3) ^ ((srow >> 1) & 3);

    const u16* gA0 = &A[(size_t)(m0 + srow) * 256 + spart * 8];
    const u16* gW1 = &w1[(size_t)srow * 256 + spart * 8];
    const u16* gW2 = &w2[(size_t)srow * 256 + spart * 8];

#define STGA(b, kk) gl16(gA0 + (kk) * 32, &Ast[b][wid * 512])
#define STGB(b, kk, W) do {                                                 \
        gl16(W + (kk) * 32,             &Bst[b][wid * 512]);                \
        gl16(W + 64 * 256 + (kk) * 32,  &Bst[b][2048 + wid * 512]);         \
        gl16(W + 128 * 256 + (kk) * 32, &Bst[b][4096 + wid * 512]);         \
        gl16(W + 192 * 256 + (kk) * 32, &Bst[b][6144 + wid * 512]);         \
    } while (0)

    // ---- phase 1: acc = A @ W1^T ----
    v4f acc[2][8] = {};
    STGA(0, 0); STGB(0, 0, gW1);
    __syncthreads();
    for (int kt = 0; kt < 8; ++kt) {
        const int cb = kt & 1, nb = cb ^ 1;
        if (kt < 7) { STGA(nb, kt + 1); STGB(nb, kt + 1, gW1); }
        else        { STGB(nb, 0, gW2); }
        v8s af[2], bf[8];
#pragma unroll
        for (int i = 0; i < 2; ++i)
            af[i] = *(const v8s*)&Ast[cb][(wm + i * 16 + ln) * 32 + qs8];
#pragma unroll
        for (int j = 0; j < 8; ++j)
            bf[j] = *(const v8s*)&Bst[cb][(wn + j * 16 + ln) * 32 + qs8];
#pragma unroll
        for (int i = 0; i < 2; ++i)
#pragma unroll
            for (int j = 0; j < 8; ++j)
                acc[i][j] = __builtin_amdgcn_mfma_f32_16x16x32_bf16(
                    af[i], bf[j], acc[i][j], 0, 0, 0);
        __syncthreads();
    }

    // ---- epilogue 1: hd -> swizzled LDS ----
#pragma unroll
    for (int i = 0; i < 2; ++i)
#pragma unroll
        for (int j = 0; j < 8; ++j) {
            int col = wn + j * 16 + ln;
            float bb = b1[col];
#pragma unroll
            for (int r = 0; r < 4; ++r) {
                int row = wm + i * 16 + q * 4 + r;
                float v = acc[i][j][r] + bb;
                v = v > 0.f ? v : 0.1f * v;
                int ch = (col >> 3) ^ (row & 15);
                hdl[row * 256 + ch * 8 + (col & 7)] = f2bf(v);
            }
        }
    __syncthreads();

    // ---- phase 2: acc2 = hd @ W2^T ----
    v4f acc2[2][8] = {};
    for (int kt = 0; kt < 8; ++kt) {
        const int cb = kt & 1, nb = cb ^ 1;
        if (kt < 7) STGB(nb, kt + 1, gW2);
        v8s af[2], bf[8];
#pragma unroll
        for (int i = 0; i < 2; ++i) {
            int row = wm + i * 16 + ln;
            int ch = (kt * 4 + q) ^ (row & 15);
            af[i] = *(const v8s*)&hdl[row * 256 + ch * 8];
        }
#pragma unroll
        for (int j = 0; j < 8; ++j)
            bf[j] = *(const v8s*)&Bst[cb][(wn + j * 16 + ln) * 32 + qs8];
#pragma unroll
        for (int i = 0; i < 2; ++i)
#pragma unroll
            for (int j = 0; j < 8; ++j)
                acc2[i][j] = __builtin_amdgcn_mfma_f32_16x16x32_bf16(
                    af[i], bf[j], acc2[i][j], 0, 0, 0);
        __syncthreads();
    }
#undef STGA
#undef STGB

    // ---- epilogue 2: leaky + W3 partial dot + butterfly over ln ----
    float part[3][2][4] = {};
#pragma unroll
    for (int j = 0; j < 8; ++j) {
        int col = wn + j * 16 + ln;
        float bb = b2[col];
        float w30 = w3[col], w31 = w3[256 + col], w32 = w3[512 + col];
#pragma unroll
        for (int i = 0; i < 2; ++i)
#pragma unroll
            for (int r = 0; r < 4; ++r) {
                float v = acc2[i][j][r] + bb;
                v = v > 0.f ? v : 0.1f * v;
                part[0][i][r] += v * w30;
                part[1][i][r] += v * w31;
                part[2][i][r] += v * w32;
            }
    }
#pragma unroll
    for (int off = 1; off < 16; off <<= 1)
#pragma unroll
        for (int t = 0; t < 3; ++t)
#pragma unroll
            for (int i = 0; i < 2; ++i)
#pragma unroll
                for (int r = 0; r < 4; ++r)
                    part[t][i][r] += __shfl_xor(part[t][i][r], off, 16);
    if (ln == 0) {
#pragma unroll
        for (int i = 0; i < 2; ++i)
#pragma unroll
            for (int r = 0; r < 4; ++r) {
                int row = wm + i * 16 + q * 4 + r;
#pragma unroll
                for (int t = 0; t < 3; ++t)
                    resl[wnh][row][t] = part[t][i][r];
            }
    }
    __syncthreads();

    // ---- in-block finisher (64 threads, one row each) ----
    if (tid < 64) {
        int m = m0 + tid;
        float s0 = resl[0][tid][0] + resl[1][tid][0];
        float s1 = resl[0][tid][1] + resl[1][tid][1];
        float s2 = resl[0][tid][2] + resl[1][tid][2];
        float a0 = p1[m * 3 + 0], a1 = p1[m * 3 + 1], a2 = p1[m * 3 + 2];
        float c0 = p2[m * 3 + 0], c1 = p2[m * 3 + 1], c2 = p2[m * 3 + 2];
        float o0 = a0 + s0 + b3[0];
        float o1 = a1 + s1 + b3[1];
        float o2 = a2 + s2 + b3[2];
        size_t ob = ((size_t)m * TS + s) * 3;
        out[ob + 0] = o0; out[ob + 1] = o1; out[ob + 2] = o2;
        pnew[m * 3 + 0] = o0; pnew[m * 3 + 1] = o1; pnew[m * 3 + 2] = o2;
        unsigned t[32];
#pragma unroll
        for (int i = 0; i < 32; ++i) t[i] = 0;
        t[0] = f2bf(o0); t[1] = f2bf(o1); t[2] = f2bf(o2);
        t[3] = f2bf(a0 - c0); t[4] = f2bf(a1 - c1); t[5] = f2bf(a2 - c2);
        t[6] = f2bf(o0 - 2.f * a0 + c0);
        t[7] = f2bf(o1 - 2.f * a1 + c1);
        t[8] = f2bf(o2 - 2.f * a2 + c2);
        t[9] = f2bf(1.f);
        uint4* dst = (uint4*)&xpad[(size_t)m * 32];
#pragma unroll
        for (int wq = 0; wq < 4; ++wq) {
            uint4 u;
            u.x = t[wq * 8 + 0] | (t[wq * 8 + 1] << 16);
            u.y = t[wq * 8 + 2] | (t[wq * 8 + 3] << 16);
            u.z = t[wq * 8 + 4] | (t[wq * 8 + 5] << 16);
            u.w = t[wq * 8 + 6] | (t[wq * 8 + 7] << 16);
            dst[wq] = u;
        }
    }
}

// ---------------------------------------------------------------------------
// Fused GRU, K=288: cols 0..255 = msg (Wh*), 256..287 = xpad (x-proj + bias).
// BYTE-EXACT R3 structure (115.5 us @ 20.4% occupancy, VGPR 116): rolled kt
// loop (NO unroll — R2's unroll cost 140 VGPR / 11% occ / 196 us), single
// LDS buffer, two barriers per K-step, constant-folded XOR swizzle.
// grid = (832, 4). DO NOT TOUCH.
// ---------------------------------------------------------------------------
__global__ __launch_bounds__(256) void gru_fused(
    const u16* __restrict__ Am, const u16* __restrict__ xpad,
    const u16* __restrict__ hprev, u16* __restrict__ hout,
    const u16* __restrict__ wfull, const u16* __restrict__ wxn)
{
    __shared__ u16 Al[128 * 32];   // 8 KB
    __shared__ u16 Bl[192 * 32];   // 12 KB
    __shared__ u16 Xl[64 * 32];    // 4 KB
    const int m0 = blockIdx.x * 128;
    const int n0 = blockIdx.y * 64;
    const int tid = threadIdx.x;
    const int wid = tid >> 6, lane = tid & 63;
    const int ln = lane & 15, q = lane >> 4;
    const int qs8 = (q ^ ((ln >> 1) & 3)) * 8;
    const int wm = (wid >> 1) * 64, wn = (wid & 1) * 32;
    const int srow = tid >> 2;
    const int spart = (tid & 3) ^ ((srow >> 1) & 3);

    // wxn tile (64 rows of this block's n0 slice), needed only at kt==8
    gl16(&wxn[(size_t)(n0 + srow) * 32 + spart * 8], &Xl[(wid * 64) * 8]);

    v4f accr[4][2] = {}, accz[4][2] = {}, acch[4][2] = {}, accn[4][2] = {};

    for (int kt = 0; kt < 9; ++kt) {
#pragma unroll
        for (int p = 0; p < 2; ++p) {
            const u16* ga = (kt < 8)
                ? &Am[(size_t)(m0 + p * 64 + srow) * 256 + kt * 32 + spart * 8]
                : &xpad[(size_t)(m0 + p * 64 + srow) * 32 + spart * 8];
            gl16(ga, &Al[(p * 256 + wid * 64) * 8]);
        }
#pragma unroll
        for (int p = 0; p < 3; ++p)
            gl16(&wfull[(size_t)(p * 256 + n0 + srow) * 288 + kt * 32 + spart * 8],
                 &Bl[(p * 256 + wid * 64) * 8]);
        __syncthreads();

        v8s af[4];
#pragma unroll
        for (int i = 0; i < 4; ++i)
            af[i] = *(const v8s*)&Al[(wm + i * 16 + ln) * 32 + qs8];
        v8s bfr[3][2];
#pragma unroll
        for (int g = 0; g < 3; ++g)
#pragma unroll
            for (int j = 0; j < 2; ++j)
                bfr[g][j] = *(const v8s*)&Bl[(g * 64 + wn + j * 16 + ln) * 32 + qs8];
#pragma unroll
        for (int i = 0; i < 4; ++i)
#pragma unroll
            for (int j = 0; j < 2; ++j) {
                accr[i][j] = __builtin_amdgcn_mfma_f32_16x16x32_bf16(af[i], bfr[0][j], accr[i][j], 0, 0, 0);
                accz[i][j] = __builtin_amdgcn_mfma_f32_16x16x32_bf16(af[i], bfr[1][j], accz[i][j], 0, 0, 0);
                acch[i][j] = __builtin_amdgcn_mfma_f32_16x16x32_bf16(af[i], bfr[2][j], acch[i][j], 0, 0, 0);
            }
        if (kt == 8) {
            v8s bfn[2];
#pragma unroll
            for (int j = 0; j < 2; ++j)
                bfn[j] = *(const v8s*)&Xl[(wn + j * 16 + ln) * 32 + qs8];
#pragma unroll
            for (int i = 0; i < 4; ++i)
#pragma unroll
                for (int j = 0; j < 2; ++j)
                    accn[i][j] = __builtin_amdgcn_mfma_f32_16x16x32_bf16(af[i], bfn[j], accn[i][j], 0, 0, 0);
        }
        __syncthreads();
    }

#pragma unroll
    for (int i = 0; i < 4; ++i)
#pragma unroll
        for (int j = 0; j < 2; ++j) {
            int gc = n0 + wn + j * 16 + ln;
#pragma unroll
            for (int r = 0; r < 4; ++r) {
                int gr = m0 + wm + i * 16 + q * 4 + r;
                float rg = sigm(accr[i][j][r]);
                float zg = sigm(accz[i][j][r]);
                float nn = tanh_fast(accn[i][j][r] + rg * acch[i][j][r]);
                float hp = bf2f(hprev[(size_t)gr * 256 + gc]);
                hout[(size_t)gr * 256 + gc] = f2bf((1.f - zg) * nn + zg * hp);
            }
        }
}

// ---------------------------------------------------------------------------
// Step-0 xpad from the three input frames.
// ---------------------------------------------------------------------------
__global__ __launch_bounds__(256) void init_xpad(
    const float* __restrict__ x0, const float* __restrict__ xp,
    const float* __restrict__ xp2, u16* __restrict__ xpad)
{
    int m = blockIdx.x * 256 + threadIdx.x;
    float a0 = x0[m * 3 + 0], a1 = x0[m * 3 + 1], a2 = x0[m * 3 + 2];
    float b0 = xp[m * 3 + 0], b1 = xp[m * 3 + 1], b2 = xp[m * 3 + 2];
    float c0 = xp2[m * 3 + 0], c1 = xp2[m * 3 + 1], c2 = xp2[m * 3 + 2];
    unsigned t[32];
#pragma unroll
    for (int i = 0; i < 32; ++i) t[i] = 0;
    t[0] = f2bf(a0); t[1] = f2bf(a1); t[2] = f2bf(a2);
    t[3] = f2bf(b0 - c0); t[4] = f2bf(b1 - c1); t[5] = f2bf(b2 - c2);
    t[6] = f2bf(a0 - 2.f * b0 + c0);
    t[7] = f2bf(a1 - 2.f * b1 + c1);
    t[8] = f2bf(a2 - 2.f * b2 + c2);
    t[9] = f2bf(1.f);
    uint4* dst = (uint4*)&xpad[(size_t)m * 32];
#pragma unroll
    for (int wq = 0; wq < 4; ++wq) {
        uint4 u;
        u.x = t[wq * 8 + 0] | (t[wq * 8 + 1] << 16);
        u.y = t[wq * 8 + 2] | (t[wq * 8 + 3] << 16);
        u.z = t[wq * 8 + 4] | (t[wq * 8 + 5] << 16);
        u.w = t[wq * 8 + 6] | (t[wq * 8 + 7] << 16);
        dst[wq] = u;
    }
}

// ---------------------------------------------------------------------------
// hidden [N,C,V] fp32 -> h[(n,v),c] bf16.
// ---------------------------------------------------------------------------
__global__ __launch_bounds__(256) void transpose_h(
    const float* __restrict__ hidden, u16* __restrict__ hA)
{
    __shared__ float hl[256 * VN];
    const int n = blockIdx.x, tid = threadIdx.x;
    const uint4* src = (const uint4*)(hidden + (size_t)n * 256 * VN);
    for (int idx = tid; idx < 256 * VN / 4; idx += 256)
        ((uint4*)hl)[idx] = src[idx];
    __syncthreads();
    size_t base = (size_t)n * VN * 256;
    for (int idx = tid; idx < VN * 256; idx += 256) {
        int v = idx >> 8, c = idx & 255;
        hA[base + idx] = f2bf(hl[c * VN + v]);
    }
}

// ---------------------------------------------------------------------------
// Weight packing (once per call).
// wfull[768,288]: row g*256+c -> cols 0..255 = Wh_g[c,:],
//   256..264 = x-weights (g<2), 265 = bias (g<2), rest 0.
// wxn[256,32]:   row c -> 0..8 = Win[c,:], 9 = b_in[c], rest 0.
// ---------------------------------------------------------------------------
__global__ __launch_bounds__(256) void pack_weights(
    const float* __restrict__ Whr, const float* __restrict__ Whi,
    const float* __restrict__ Whh, const float* __restrict__ convw_f,
    const float* __restrict__ W1f, const float* __restrict__ W2f,
    const float* __restrict__ Af, const float* __restrict__ emul,
    const float* __restrict__ eadd, const float* __restrict__ Wir,
    const float* __restrict__ Wii, const float* __restrict__ Win,
    const float* __restrict__ bir, const float* __restrict__ bii,
    const float* __restrict__ b_in, const float* __restrict__ convb_f,
    const float* __restrict__ b1f, const float* __restrict__ b2f,
    const float* __restrict__ W3f, const float* __restrict__ b3f,
    u16* __restrict__ wfull, u16* __restrict__ wxn, u16* __restrict__ convw,
    u16* __restrict__ w1, u16* __restrict__ w2, float* __restrict__ aadj,
    float* __restrict__ convb, float* __restrict__ b1, float* __restrict__ b2,
    float* __restrict__ w3, float* __restrict__ b3)
{
    int gid = blockIdx.x * 256 + threadIdx.x;
    int stride = gridDim.x * 256;
    for (int i = gid; i < 768 * 288; i += stride) {
        int row = i / 288, col = i - row * 288;
        int g = row >> 8, c = row & 255;
        float v = 0.f;
        if (col < 256)
            v = (g == 0 ? Whr : (g == 1 ? Whi : Whh))[c * 256 + col];
        else if (col < 265) {
            int tcol = col - 256;
            v = (g == 0 ? Wir[c * 9 + tcol] : (g == 1 ? Wii[c * 9 + tcol] : 0.f));
        } else if (col == 265)
            v = (g == 0 ? bir[c] : (g == 1 ? bii[c] : 0.f));
        wfull[i] = f2bf(v);
    }
    for (int i = gid; i < 256 * 32; i += stride) {
        int c = i >> 5, col = i & 31;
        float v = 0.f;
        if (col < 9) v = Win[c * 9 + col];
        else if (col == 9) v = b_in[c];
        wxn[i] = f2bf(v);
    }
    for (int i = gid; i < 65536; i += stride) {
        w1[i] = f2bf(W1f[i]);
        w2[i] = f2bf(W2f[i]);
    }
    for (int i = gid; i < 196608; i += stride) convw[i] = f2bf(convw_f[i]);
    for (int i = gid; i < KNUM * VN * VN; i += stride)
        aadj[i] = Af[i] * emul[i] + eadd[i];
    for (int i = gid; i < 256; i += stride) { b1[i] = b1f[i]; b2[i] = b2f[i]; }
    for (int i = gid; i < 768; i += stride) { convb[i] = convb_f[i]; w3[i] = W3f[i]; }
    if (gid < 3) b3[gid] = b3f[gid];
}

// ---------------------------------------------------------------------------
extern "C" void kernel_launch(void* const* d_in, const int* in_sizes, int n_in,
                              void* d_out, int out_size, void* d_ws, size_t ws_size,
                              hipStream_t stream)
{
    const float* inputs   = (const float*)d_in[0];
    const float* inputs_p = (const float*)d_in[1];
    const float* inputs_p2= (const float*)d_in[2];
    const float* hidden   = (const float*)d_in[3];
    const float* Af       = (const float*)d_in[4];
    const float* emul     = (const float*)d_in[5];
    const float* eadd     = (const float*)d_in[6];
    const float* conv_w   = (const float*)d_in[7];
    const float* conv_b   = (const float*)d_in[8];
    const float* Wir      = (const float*)d_in[9];
    const float* bir      = (const float*)d_in[10];
    const float* Wii      = (const float*)d_in[11];
    const float* bii      = (const float*)d_in[12];
    const float* Win      = (const float*)d_in[13];
    const float* b_in     = (const float*)d_in[14];
    const float* Whr      = (const float*)d_in[15];
    const float* Whi      = (const float*)d_in[16];
    const float* Whh      = (const float*)d_in[17];
    const float* W1f      = (const float*)d_in[18];
    const float* b1f      = (const float*)d_in[19];
    const float* W2f      = (const float*)d_in[20];
    const float* b2f      = (const float*)d_in[21];
    const float* W3f      = (const float*)d_in[22];
    const float* b3f      = (const float*)d_in[23];
    float* out = (float*)d_out;

    const size_t M = M_ROWS;
    char* ws = (char*)d_ws;
    size_t off = 0;
    auto alloc = [&](size_t bytes) -> void* {
        void* p = ws + off;
        off = (off + bytes + 255) & ~(size_t)255;
        return p;
    };
    // R3/R5/R7-exact allocation order (gru's measured environment). ybuf is
    // unused but kept so every later buffer keeps its address.
    u16* hA    = (u16*)alloc(M * 256 * 2);
    u16* hB    = (u16*)alloc(M * 256 * 2);
    u16* msg   = (u16*)alloc(M * 256 * 2);
    u16* ybuf  = (u16*)alloc(M * 768 * 2);
    u16* xpad  = (u16*)alloc(M * 32 * 2);
    float* pa  = (float*)alloc(M * 3 * 4);
    float* pb  = (float*)alloc(M * 3 * 4);
    float* pc  = (float*)alloc(M * 3 * 4);
    u16* wfull = (u16*)alloc(768 * 288 * 2);
    u16* wxn   = (u16*)alloc(256 * 32 * 2);
    u16* convw = (u16*)alloc(196608 * 2);
    u16* w1    = (u16*)alloc(65536 * 2);
    u16* w2    = (u16*)alloc(65536 * 2);
    float* aadj  = (float*)alloc(KNUM * VN * VN * 4);
    float* convb = (float*)alloc(768 * 4);
    float* b1    = (float*)alloc(256 * 4);
    float* b2    = (float*)alloc(256 * 4);
    float* w3    = (float*)alloc(768 * 4);
    float* b3    = (float*)alloc(16);
    (void)ybuf;
    if (off > ws_size) return;

    pack_weights<<<512, 256, 0, stream>>>(
        Whr, Whi, Whh, conv_w, W1f, W2f, Af, emul, eadd, Wir, Wii, Win,
        bir, bii, b_in, conv_b, b1f, b2f, W3f, b3f,
        wfull, wxn, convw, w1, w2, aadj, convb, b1, b2, w3, b3);
    transpose_h<<<NBATCH, 256, 0, stream>>>(hidden, hA);
    init_xpad<<<M_ROWS / 256, 256, 0, stream>>>(inputs, inputs_p, inputs_p2, xpad);
    hipMemcpyAsync(pa, inputs,    M * 3 * 4, hipMemcpyDeviceToDevice, stream);
    hipMemcpyAsync(pb, inputs_p,  M * 3 * 4, hipMemcpyDeviceToDevice, stream);
    hipMemcpyAsync(pc, inputs_p2, M * 3 * 4, hipMemcpyDeviceToDevice, stream);

    u16* hcur = hA;  u16* hnext = hB;
    float* P1 = pa;  float* P2 = pb;  float* P3 = pc;
    const int MB = M_ROWS / 128;  // 832

    for (int s = 0; s < TS; ++s) {
        const u16* m_ptr;
        if (s < 10) {
            // conv gemm + graph mix fused; y-panel stays in LDS
            conv_mix<<<NBATCH, 256, 0, stream>>>(hcur, convw, convb, aadj, msg);
            m_ptr = msg;
        } else {
            m_ptr = hcur;
        }
        gru_fused<<<dim3(MB, 4), 256, 0, stream>>>(m_ptr, xpad, hcur, hnext,
                                                   wfull, wxn);
        // W1+W2+W3+finisher fused: hd/hd2 never touch HBM
        mlp_head<<<M_ROWS / 64, 256, 0, stream>>>(hnext, w1, b1, w2, b2, w3, b3,
                                                  P1, P2, P3, xpad, out, s);
        float* t = P3; P3 = P2; P2 = P1; P1 = t;
        u16* ht = hcur; hcur = hnext; hnext = ht;
    }
}

// Round 10
// 5510.474 us; speedup vs baseline: 1.1579x; 1.0812x over previous
//
#include <hip/hip_runtime.h>

// Problem constants (fixed by the reference)
#define M_ROWS 106496   // 4096*26  (n,v) rows
#define NBATCH 4096
#define VN 26
#define KNUM 3
#define TS 25

typedef unsigned short u16;
typedef __attribute__((ext_vector_type(8))) short v8s;
typedef __attribute__((ext_vector_type(4))) float v4f;

__device__ __forceinline__ u16 f2bf(float f) {
    unsigned u = __float_as_uint(f);
    u += 0x7FFF + ((u >> 16) & 1);   // RNE
    return (u16)(u >> 16);
}
__device__ __forceinline__ float bf2f(u16 h) {
    return __uint_as_float(((unsigned)h) << 16);
}
__device__ __forceinline__ float sigm(float x) {
    return 1.f / (1.f + __expf(-x));
}
__device__ __forceinline__ float tanh_fast(float x) {
    return 2.f / (1.f + __expf(-2.f * x)) - 1.f;
}

// Async global->LDS, 16B per lane. LDS dest must be the wave-uniform base;
// HW adds lane*16. Staging layout stays LINEAR in lane order; the LDS
// swizzle is realized by pre-permuting the per-lane GLOBAL source chunk
// (rule: both-sides-or-neither with global_load_lds).
typedef const __attribute__((address_space(1))) unsigned int* gas_t;
typedef __attribute__((address_space(3))) unsigned int* las_t;
__device__ __forceinline__ void gl16(const void* g, void* l) {
    __builtin_amdgcn_global_load_lds((gas_t)g, (las_t)l, 16, 0, 0);
}

// ---------------------------------------------------------------------------
// Fused conv-gemm + graph mix, one block per batch n.
// R10 change: the mix (26x256x78 per n) is MFMA-ized. R7/R9 counters show
// the old per-thread mix (78 serial load->26-FMA chains, 2028 VALU FMAs)
// dominated VALU issue (~6x the GEMM's MFMA cycles) and was invariant to
// both prior fixes. Now the conv epilogue writes y TRANSPOSED into
// Yt[c][k*32+v] (48 KB LDS, zero-padded K=96) and the mix is 48 MFMAs/wave
// against a bf16 hi/lo split of aadjT (y is exact bf16, so y*(hi+lo)
// recovers aadj to ~2^-17 rel; only fp32 sum ORDER changes, ~1e-6 abs).
// To fit LDS, H's 16K pre-stage is replaced by the known-good per-kt gl16
// A-tile (2 KB, gemm_nt pattern; junk rows 26..31 discarded by row guard).
// aadjt fragments load from L2-resident global at mix time only — no new
// live state across the GEMM (R8 occupancy lesson).
// LDS: Al 2K + Bst 24K + Yt 48K = 74 KB -> 2 blocks/CU.
// ---------------------------------------------------------------------------
__global__ __launch_bounds__(256) void conv_mix(
    const u16* __restrict__ h, const u16* __restrict__ convw,
    const float* __restrict__ convb, const u16* __restrict__ aadjt,
    u16* __restrict__ msg)
{
    __shared__ u16 Al[32 * 32];      // 2 KB per-kt A tile (swizzled chunks)
    __shared__ u16 Bst[384 * 32];    // 24 KB weight tile
    __shared__ u16 Yt[256 * 96];     // 48 KB y^T panel: [c][k*32+v]
    const int n = blockIdx.x, tid = threadIdx.x;
    const int wid = tid >> 6, lane = tid & 63;
    const int ln = lane & 15, q = lane >> 4;
    const int qs8 = (q ^ ((ln >> 1) & 3)) * 8;
    const int wn = wid * 96;                 // 96 of 384 cols per wave (conv)
    const int srow = tid >> 2;
    const int spart = (tid & 3) ^ ((srow >> 1) & 3);

    // zero Yt once (the v=26..31 pads per k-section must be 0)
    {
        uint4 z = {0, 0, 0, 0};
        for (int i4 = tid; i4 < 256 * 96 / 8; i4 += 256) ((uint4*)Yt)[i4] = z;
    }

    // A source: rows 26..31 over-read into the next region (allocated);
    // they only produce acc rows >= 26, which the epilogue discards.
    const u16* gA0 = &h[((size_t)n * 26 + srow) * 256 + spart * 8];
    const u16* gW0 = &convw[(size_t)srow * 256 + spart * 8];

    for (int p = 0; p < 2; ++p) {
        v4f acc[2][6] = {};
        const u16* gW = gW0 + (size_t)p * 384 * 256;
        for (int kt = 0; kt < 8; ++kt) {
            if (wid < 2) gl16(gA0 + kt * 32, &Al[wid * 512]);
#pragma unroll
            for (int t = 0; t < 6; ++t)
                gl16(gW + (size_t)t * 64 * 256 + kt * 32,
                     &Bst[t * 2048 + wid * 512]);
            __syncthreads();
            v8s af[2], bf[6];
#pragma unroll
            for (int i = 0; i < 2; ++i)
                af[i] = *(const v8s*)&Al[(i * 16 + ln) * 32 + qs8];
#pragma unroll
            for (int j = 0; j < 6; ++j)
                bf[j] = *(const v8s*)&Bst[(wn + j * 16 + ln) * 32 + qs8];
#pragma unroll
            for (int i = 0; i < 2; ++i)
#pragma unroll
                for (int j = 0; j < 6; ++j)
                    acc[i][j] = __builtin_amdgcn_mfma_f32_16x16x32_bf16(
                        af[i], bf[j], acc[i][j], 0, 0, 0);
            __syncthreads();
        }
        // epilogue: y rows < 26 -> Yt[c][k*32+v], bf16 at the SAME rounding
        // point as the original ybuf store
#pragma unroll
        for (int i = 0; i < 2; ++i)
#pragma unroll
            for (int j = 0; j < 6; ++j) {
                int o = p * 384 + wn + j * 16 + ln;   // global y column
                int k = o >> 8, c = o & 255;
                float cb = convb[o];
#pragma unroll
                for (int r = 0; r < 4; ++r) {
                    int v = i * 16 + q * 4 + r;
                    if (v < 26)
                        Yt[c * 96 + k * 32 + v] = f2bf(acc[i][j][r] + cb);
                }
            }
    }
    __syncthreads();   // all Yt writes visible

    // ---- mix via MFMA: msg[w][c] = sum_kv aadjT[w][kv] * Yt[c][kv] ----
    // aadjt: [2][32][96] bf16 (hi then lo), rows w pad>=26 zero, v pads zero.
    const int wnm = wid * 64;                // 64 of 256 cols per wave (mix)
    v4f macc[2][4] = {};
#pragma unroll
    for (int kt = 0; kt < 3; ++kt) {
        v8s ah[2], alo[2], bf[4];
#pragma unroll
        for (int i = 0; i < 2; ++i) {
            ah[i]  = *(const v8s*)&aadjt[(size_t)(i * 16 + ln) * 96 + kt * 32 + q * 8];
            alo[i] = *(const v8s*)&aadjt[(size_t)32 * 96 +
                                         (size_t)(i * 16 + ln) * 96 + kt * 32 + q * 8];
        }
#pragma unroll
        for (int j = 0; j < 4; ++j)
            bf[j] = *(const v8s*)&Yt[(wnm + j * 16 + ln) * 96 + kt * 32 + q * 8];
#pragma unroll
        for (int i = 0; i < 2; ++i)
#pragma unroll
            for (int j = 0; j < 4; ++j) {
                macc[i][j] = __builtin_amdgcn_mfma_f32_16x16x32_bf16(
                    ah[i], bf[j], macc[i][j], 0, 0, 0);
                macc[i][j] = __builtin_amdgcn_mfma_f32_16x16x32_bf16(
                    alo[i], bf[j], macc[i][j], 0, 0, 0);
            }
    }
    size_t base = (size_t)n * VN * 256;
#pragma unroll
    for (int i = 0; i < 2; ++i)
#pragma unroll
        for (int j = 0; j < 4; ++j) {
            int c = wnm + j * 16 + ln;
#pragma unroll
            for (int r = 0; r < 4; ++r) {
                int w = i * 16 + q * 4 + r;
                if (w < 26) msg[base + (size_t)w * 256 + c] = f2bf(macc[i][j][r]);
            }
        }
}

// ---------------------------------------------------------------------------
// Fused MLP head: one kernel for W1 -> W2 -> W3 -> finisher (R5-exact,
// measured good). BM=64 rows/block, grid 1664. hd/hd2 never touch HBM.
// ---------------------------------------------------------------------------
__global__ __launch_bounds__(256) void mlp_head(
    const u16* __restrict__ A, const u16* __restrict__ w1,
    const float* __restrict__ b1, const u16* __restrict__ w2,
    const float* __restrict__ b2, const float* __restrict__ w3,
    const float* __restrict__ b3, const float* __restrict__ p1,
    const float* __restrict__ p2, float* __restrict__ pnew,
    u16* __restrict__ xpad, float* __restrict__ out, int s)
{
    __shared__ u16 Ast[2][64 * 32];     // 2 x 4 KB
    __shared__ u16 Bst[2][256 * 32];    // 2 x 16 KB
    __shared__ u16 hdl[64 * 256];       // 32 KB, chunk-XOR swizzled
    __shared__ float resl[2][64][3];    // 1.5 KB
    const int m0 = blockIdx.x * 64;
    const int tid = threadIdx.x;
    const int wid = tid >> 6, lane = tid & 63;
    const int ln = lane & 15, q = lane >> 4;
    const int qs8 = (q ^ ((ln >> 1) & 3)) * 8;
    const int wm = (wid >> 1) * 32;     // 0 / 32
    const int wn = (wid & 1) * 128;     // 0 / 128
    const int wnh = wid & 1;
    const int srow = tid >> 2;
    const int spart = (tid & 3) ^ ((srow >> 1) & 3);

    const u16* gA0 = &A[(size_t)(m0 + srow) * 256 + spart * 8];
    const u16* gW1 = &w1[(size_t)srow * 256 + spart * 8];
    const u16* gW2 = &w2[(size_t)srow * 256 + spart * 8];

#define STGA(b, kk) gl16(gA0 + (kk) * 32, &Ast[b][wid * 512])
#define STGB(b, kk, W) do {                                                 \
        gl16(W + (kk) * 32,             &Bst[b][wid * 512]);                \
        gl16(W + 64 * 256 + (kk) * 32,  &Bst[b][2048 + wid * 512]);         \
        gl16(W + 128 * 256 + (kk) * 32, &Bst[b][4096 + wid * 512]);         \
        gl16(W + 192 * 256 + (kk) * 32, &Bst[b][6144 + wid * 512]);         \
    } while (0)

    // ---- phase 1: acc = A @ W1^T ----
    v4f acc[2][8] = {};
    STGA(0, 0); STGB(0, 0, gW1);
    __syncthreads();
    for (int kt = 0; kt < 8; ++kt) {
        const int cb = kt & 1, nb = cb ^ 1;
        if (kt < 7) { STGA(nb, kt + 1); STGB(nb, kt + 1, gW1); }
        else        { STGB(nb, 0, gW2); }
        v8s af[2], bf[8];
#pragma unroll
        for (int i = 0; i < 2; ++i)
            af[i] = *(const v8s*)&Ast[cb][(wm + i * 16 + ln) * 32 + qs8];
#pragma unroll
        for (int j = 0; j < 8; ++j)
            bf[j] = *(const v8s*)&Bst[cb][(wn + j * 16 + ln) * 32 + qs8];
#pragma unroll
        for (int i = 0; i < 2; ++i)
#pragma unroll
            for (int j = 0; j < 8; ++j)
                acc[i][j] = __builtin_amdgcn_mfma_f32_16x16x32_bf16(
                    af[i], bf[j], acc[i][j], 0, 0, 0);
        __syncthreads();
    }

    // ---- epilogue 1: hd -> swizzled LDS ----
#pragma unroll
    for (int i = 0; i < 2; ++i)
#pragma unroll
        for (int j = 0; j < 8; ++j) {
            int col = wn + j * 16 + ln;
            float bb = b1[col];
#pragma unroll
            for (int r = 0; r < 4; ++r) {
                int row = wm + i * 16 + q * 4 + r;
                float v = acc[i][j][r] + bb;
                v = v > 0.f ? v : 0.1f * v;
                int ch = (col >> 3) ^ (row & 15);
                hdl[row * 256 + ch * 8 + (col & 7)] = f2bf(v);
            }
        }
    __syncthreads();

    // ---- phase 2: acc2 = hd @ W2^T ----
    v4f acc2[2][8] = {};
    for (int kt = 0; kt < 8; ++kt) {
        const int cb = kt & 1, nb = cb ^ 1;
        if (kt < 7) STGB(nb, kt + 1, gW2);
        v8s af[2], bf[8];
#pragma unroll
        for (int i = 0; i < 2; ++i) {
            int row = wm + i * 16 + ln;
            int ch = (kt * 4 + q) ^ (row & 15);
            af[i] = *(const v8s*)&hdl[row * 256 + ch * 8];
        }
#pragma unroll
        for (int j = 0; j < 8; ++j)
            bf[j] = *(const v8s*)&Bst[cb][(wn + j * 16 + ln) * 32 + qs8];
#pragma unroll
        for (int i = 0; i < 2; ++i)
#pragma unroll
            for (int j = 0; j < 8; ++j)
                acc2[i][j] = __builtin_amdgcn_mfma_f32_16x16x32_bf16(
                    af[i], bf[j], acc2[i][j], 0, 0, 0);
        __syncthreads();
    }
#undef STGA
#undef STGB

    // ---- epilogue 2: leaky + W3 partial dot + butterfly over ln ----
    float part[3][2][4] = {};
#pragma unroll
    for (int j = 0; j < 8; ++j) {
        int col = wn + j * 16 + ln;
        float bb = b2[col];
        float w30 = w3[col], w31 = w3[256 + col], w32 = w3[512 + col];
#pragma unroll
        for (int i = 0; i < 2; ++i)
#pragma unroll
            for (int r = 0; r < 4; ++r) {
                float v = acc2[i][j][r] + bb;
                v = v > 0.f ? v : 0.1f * v;
                part[0][i][r] += v * w30;
                part[1][i][r] += v * w31;
                part[2][i][r] += v * w32;
            }
    }
#pragma unroll
    for (int off = 1; off < 16; off <<= 1)
#pragma unroll
        for (int t = 0; t < 3; ++t)
#pragma unroll
            for (int i = 0; i < 2; ++i)
#pragma unroll
                for (int r = 0; r < 4; ++r)
                    part[t][i][r] += __shfl_xor(part[t][i][r], off, 16);
    if (ln == 0) {
#pragma unroll
        for (int i = 0; i < 2; ++i)
#pragma unroll
            for (int r = 0; r < 4; ++r) {
                int row = wm + i * 16 + q * 4 + r;
#pragma unroll
                for (int t = 0; t < 3; ++t)
                    resl[wnh][row][t] = part[t][i][r];
            }
    }
    __syncthreads();

    // ---- in-block finisher (64 threads, one row each) ----
    if (tid < 64) {
        int m = m0 + tid;
        float s0 = resl[0][tid][0] + resl[1][tid][0];
        float s1 = resl[0][tid][1] + resl[1][tid][1];
        float s2 = resl[0][tid][2] + resl[1][tid][2];
        float a0 = p1[m * 3 + 0], a1 = p1[m * 3 + 1], a2 = p1[m * 3 + 2];
        float c0 = p2[m * 3 + 0], c1 = p2[m * 3 + 1], c2 = p2[m * 3 + 2];
        float o0 = a0 + s0 + b3[0];
        float o1 = a1 + s1 + b3[1];
        float o2 = a2 + s2 + b3[2];
        size_t ob = ((size_t)m * TS + s) * 3;
        out[ob + 0] = o0; out[ob + 1] = o1; out[ob + 2] = o2;
        pnew[m * 3 + 0] = o0; pnew[m * 3 + 1] = o1; pnew[m * 3 + 2] = o2;
        unsigned t[32];
#pragma unroll
        for (int i = 0; i < 32; ++i) t[i] = 0;
        t[0] = f2bf(o0); t[1] = f2bf(o1); t[2] = f2bf(o2);
        t[3] = f2bf(a0 - c0); t[4] = f2bf(a1 - c1); t[5] = f2bf(a2 - c2);
        t[6] = f2bf(o0 - 2.f * a0 + c0);
        t[7] = f2bf(o1 - 2.f * a1 + c1);
        t[8] = f2bf(o2 - 2.f * a2 + c2);
        t[9] = f2bf(1.f);
        uint4* dst = (uint4*)&xpad[(size_t)m * 32];
#pragma unroll
        for (int wq = 0; wq < 4; ++wq) {
            uint4 u;
            u.x = t[wq * 8 + 0] | (t[wq * 8 + 1] << 16);
            u.y = t[wq * 8 + 2] | (t[wq * 8 + 3] << 16);
            u.z = t[wq * 8 + 4] | (t[wq * 8 + 5] << 16);
            u.w = t[wq * 8 + 6] | (t[wq * 8 + 7] << 16);
            dst[wq] = u;
        }
    }
}

// ---------------------------------------------------------------------------
// Fused GRU, K=288: cols 0..255 = msg (Wh*), 256..287 = xpad (x-proj + bias).
// BYTE-EXACT R3 structure (115.5 us @ 20.4% occupancy, VGPR 116): rolled kt
// loop (NO unroll — R2's unroll cost 140 VGPR / 11% occ / 196 us), single
// LDS buffer, two barriers per K-step, constant-folded XOR swizzle.
// grid = (832, 4). DO NOT TOUCH.
// ---------------------------------------------------------------------------
__global__ __launch_bounds__(256) void gru_fused(
    const u16* __restrict__ Am, const u16* __restrict__ xpad,
    const u16* __restrict__ hprev, u16* __restrict__ hout,
    const u16* __restrict__ wfull, const u16* __restrict__ wxn)
{
    __shared__ u16 Al[128 * 32];   // 8 KB
    __shared__ u16 Bl[192 * 32];   // 12 KB
    __shared__ u16 Xl[64 * 32];    // 4 KB
    const int m0 = blockIdx.x * 128;
    const int n0 = blockIdx.y * 64;
    const int tid = threadIdx.x;
    const int wid = tid >> 6, lane = tid & 63;
    const int ln = lane & 15, q = lane >> 4;
    const int qs8 = (q ^ ((ln >> 1) & 3)) * 8;
    const int wm = (wid >> 1) * 64, wn = (wid & 1) * 32;
    const int srow = tid >> 2;
    const int spart = (tid & 3) ^ ((srow >> 1) & 3);

    // wxn tile (64 rows of this block's n0 slice), needed only at kt==8
    gl16(&wxn[(size_t)(n0 + srow) * 32 + spart * 8], &Xl[(wid * 64) * 8]);

    v4f accr[4][2] = {}, accz[4][2] = {}, acch[4][2] = {}, accn[4][2] = {};

    for (int kt = 0; kt < 9; ++kt) {
#pragma unroll
        for (int p = 0; p < 2; ++p) {
            const u16* ga = (kt < 8)
                ? &Am[(size_t)(m0 + p * 64 + srow) * 256 + kt * 32 + spart * 8]
                : &xpad[(size_t)(m0 + p * 64 + srow) * 32 + spart * 8];
            gl16(ga, &Al[(p * 256 + wid * 64) * 8]);
        }
#pragma unroll
        for (int p = 0; p < 3; ++p)
            gl16(&wfull[(size_t)(p * 256 + n0 + srow) * 288 + kt * 32 + spart * 8],
                 &Bl[(p * 256 + wid * 64) * 8]);
        __syncthreads();

        v8s af[4];
#pragma unroll
        for (int i = 0; i < 4; ++i)
            af[i] = *(const v8s*)&Al[(wm + i * 16 + ln) * 32 + qs8];
        v8s bfr[3][2];
#pragma unroll
        for (int g = 0; g < 3; ++g)
#pragma unroll
            for (int j = 0; j < 2; ++j)
                bfr[g][j] = *(const v8s*)&Bl[(g * 64 + wn + j * 16 + ln) * 32 + qs8];
#pragma unroll
        for (int i = 0; i < 4; ++i)
#pragma unroll
            for (int j = 0; j < 2; ++j) {
                accr[i][j] = __builtin_amdgcn_mfma_f32_16x16x32_bf16(af[i], bfr[0][j], accr[i][j], 0, 0, 0);
                accz[i][j] = __builtin_amdgcn_mfma_f32_16x16x32_bf16(af[i], bfr[1][j], accz[i][j], 0, 0, 0);
                acch[i][j] = __builtin_amdgcn_mfma_f32_16x16x32_bf16(af[i], bfr[2][j], acch[i][j], 0, 0, 0);
            }
        if (kt == 8) {
            v8s bfn[2];
#pragma unroll
            for (int j = 0; j < 2; ++j)
                bfn[j] = *(const v8s*)&Xl[(wn + j * 16 + ln) * 32 + qs8];
#pragma unroll
            for (int i = 0; i < 4; ++i)
#pragma unroll
                for (int j = 0; j < 2; ++j)
                    accn[i][j] = __builtin_amdgcn_mfma_f32_16x16x32_bf16(af[i], bfn[j], accn[i][j], 0, 0, 0);
        }
        __syncthreads();
    }

#pragma unroll
    for (int i = 0; i < 4; ++i)
#pragma unroll
        for (int j = 0; j < 2; ++j) {
            int gc = n0 + wn + j * 16 + ln;
#pragma unroll
            for (int r = 0; r < 4; ++r) {
                int gr = m0 + wm + i * 16 + q * 4 + r;
                float rg = sigm(accr[i][j][r]);
                float zg = sigm(accz[i][j][r]);
                float nn = tanh_fast(accn[i][j][r] + rg * acch[i][j][r]);
                float hp = bf2f(hprev[(size_t)gr * 256 + gc]);
                hout[(size_t)gr * 256 + gc] = f2bf((1.f - zg) * nn + zg * hp);
            }
        }
}

// ---------------------------------------------------------------------------
// Step-0 xpad from the three input frames.
// ---------------------------------------------------------------------------
__global__ __launch_bounds__(256) void init_xpad(
    const float* __restrict__ x0, const float* __restrict__ xp,
    const float* __restrict__ xp2, u16* __restrict__ xpad)
{
    int m = blockIdx.x * 256 + threadIdx.x;
    float a0 = x0[m * 3 + 0], a1 = x0[m * 3 + 1], a2 = x0[m * 3 + 2];
    float b0 = xp[m * 3 + 0], b1 = xp[m * 3 + 1], b2 = xp[m * 3 + 2];
    float c0 = xp2[m * 3 + 0], c1 = xp2[m * 3 + 1], c2 = xp2[m * 3 + 2];
    unsigned t[32];
#pragma unroll
    for (int i = 0; i < 32; ++i) t[i] = 0;
    t[0] = f2bf(a0); t[1] = f2bf(a1); t[2] = f2bf(a2);
    t[3] = f2bf(b0 - c0); t[4] = f2bf(b1 - c1); t[5] = f2bf(b2 - c2);
    t[6] = f2bf(a0 - 2.f * b0 + c0);
    t[7] = f2bf(a1 - 2.f * b1 + c1);
    t[8] = f2bf(a2 - 2.f * b2 + c2);
    t[9] = f2bf(1.f);
    uint4* dst = (uint4*)&xpad[(size_t)m * 32];
#pragma unroll
    for (int wq = 0; wq < 4; ++wq) {
        uint4 u;
        u.x = t[wq * 8 + 0] | (t[wq * 8 + 1] << 16);
        u.y = t[wq * 8 + 2] | (t[wq * 8 + 3] << 16);
        u.z = t[wq * 8 + 4] | (t[wq * 8 + 5] << 16);
        u.w = t[wq * 8 + 6] | (t[wq * 8 + 7] << 16);
        dst[wq] = u;
    }
}

// ---------------------------------------------------------------------------
// hidden [N,C,V] fp32 -> h[(n,v),c] bf16.
// ---------------------------------------------------------------------------
__global__ __launch_bounds__(256) void transpose_h(
    const float* __restrict__ hidden, u16* __restrict__ hA)
{
    __shared__ float hl[256 * VN];
    const int n = blockIdx.x, tid = threadIdx.x;
    const uint4* src = (const uint4*)(hidden + (size_t)n * 256 * VN);
    for (int idx = tid; idx < 256 * VN / 4; idx += 256)
        ((uint4*)hl)[idx] = src[idx];
    __syncthreads();
    size_t base = (size_t)n * VN * 256;
    for (int idx = tid; idx < VN * 256; idx += 256) {
        int v = idx >> 8, c = idx & 255;
        hA[base + idx] = f2bf(hl[c * VN + v]);
    }
}

// ---------------------------------------------------------------------------
// Weight packing (once per call).
// wfull[768,288]: row g*256+c -> cols 0..255 = Wh_g[c,:],
//   256..264 = x-weights (g<2), 265 = bias (g<2), rest 0.
// wxn[256,32]:   row c -> 0..8 = Win[c,:], 9 = b_in[c], rest 0.
// aadjt[2][32][96] bf16: hi then lo of aadjT[w][k*32+v] (pads zero);
//   hi = bf16(aadj), lo = bf16(aadj - hi) — y*(hi+lo) recovers aadj ~2^-17.
// ---------------------------------------------------------------------------
__global__ __launch_bounds__(256) void pack_weights(
    const float* __restrict__ Whr, const float* __restrict__ Whi,
    const float* __restrict__ Whh, const float* __restrict__ convw_f,
    const float* __restrict__ W1f, const float* __restrict__ W2f,
    const float* __restrict__ Af, const float* __restrict__ emul,
    const float* __restrict__ eadd, const float* __restrict__ Wir,
    const float* __restrict__ Wii, const float* __restrict__ Win,
    const float* __restrict__ bir, const float* __restrict__ bii,
    const float* __restrict__ b_in, const float* __restrict__ convb_f,
    const float* __restrict__ b1f, const float* __restrict__ b2f,
    const float* __restrict__ W3f, const float* __restrict__ b3f,
    u16* __restrict__ wfull, u16* __restrict__ wxn, u16* __restrict__ convw,
    u16* __restrict__ w1, u16* __restrict__ w2, u16* __restrict__ aadjt,
    float* __restrict__ convb, float* __restrict__ b1, float* __restrict__ b2,
    float* __restrict__ w3, float* __restrict__ b3)
{
    int gid = blockIdx.x * 256 + threadIdx.x;
    int stride = gridDim.x * 256;
    for (int i = gid; i < 768 * 288; i += stride) {
        int row = i / 288, col = i - row * 288;
        int g = row >> 8, c = row & 255;
        float v = 0.f;
        if (col < 256)
            v = (g == 0 ? Whr : (g == 1 ? Whi : Whh))[c * 256 + col];
        else if (col < 265) {
            int tcol = col - 256;
            v = (g == 0 ? Wir[c * 9 + tcol] : (g == 1 ? Wii[c * 9 + tcol] : 0.f));
        } else if (col == 265)
            v = (g == 0 ? bir[c] : (g == 1 ? bii[c] : 0.f));
        wfull[i] = f2bf(v);
    }
    for (int i = gid; i < 256 * 32; i += stride) {
        int c = i >> 5, col = i & 31;
        float v = 0.f;
        if (col < 9) v = Win[c * 9 + col];
        else if (col == 9) v = b_in[c];
        wxn[i] = f2bf(v);
    }
    for (int i = gid; i < 65536; i += stride) {
        w1[i] = f2bf(W1f[i]);
        w2[i] = f2bf(W2f[i]);
    }
    for (int i = gid; i < 196608; i += stride) convw[i] = f2bf(convw_f[i]);
    for (int i = gid; i < 2 * 32 * 96; i += stride) {
        int hh = i / (32 * 96), rem = i - hh * 32 * 96;
        int w = rem / 96, kvp = rem - w * 96;
        int k = kvp >> 5, v = kvp & 31;
        float val = 0.f;
        if (w < 26 && v < 26) {
            int idx = (k * 26 + v) * 26 + w;
            val = Af[idx] * emul[idx] + eadd[idx];
        }
        u16 hi = f2bf(val);
        aadjt[i] = (hh == 0) ? hi : f2bf(val - bf2f(hi));
    }
    for (int i = gid; i < 256; i += stride) { b1[i] = b1f[i]; b2[i] = b2f[i]; }
    for (int i = gid; i < 768; i += stride) { convb[i] = convb_f[i]; w3[i] = W3f[i]; }
    if (gid < 3) b3[gid] = b3f[gid];
}

// ---------------------------------------------------------------------------
extern "C" void kernel_launch(void* const* d_in, const int* in_sizes, int n_in,
                              void* d_out, int out_size, void* d_ws, size_t ws_size,
                              hipStream_t stream)
{
    const float* inputs   = (const float*)d_in[0];
    const float* inputs_p = (const float*)d_in[1];
    const float* inputs_p2= (const float*)d_in[2];
    const float* hidden   = (const float*)d_in[3];
    const float* Af       = (const float*)d_in[4];
    const float* emul     = (const float*)d_in[5];
    const float* eadd     = (const float*)d_in[6];
    const float* conv_w   = (const float*)d_in[7];
    const float* conv_b   = (const float*)d_in[8];
    const float* Wir      = (const float*)d_in[9];
    const float* bir      = (const float*)d_in[10];
    const float* Wii      = (const float*)d_in[11];
    const float* bii      = (const float*)d_in[12];
    const float* Win      = (const float*)d_in[13];
    const float* b_in     = (const float*)d_in[14];
    const float* Whr      = (const float*)d_in[15];
    const float* Whi      = (const float*)d_in[16];
    const float* Whh      = (const float*)d_in[17];
    const float* W1f      = (const float*)d_in[18];
    const float* b1f      = (const float*)d_in[19];
    const float* W2f      = (const float*)d_in[20];
    const float* b2f      = (const float*)d_in[21];
    const float* W3f      = (const float*)d_in[22];
    const float* b3f      = (const float*)d_in[23];
    float* out = (float*)d_out;

    const size_t M = M_ROWS;
    char* ws = (char*)d_ws;
    size_t off = 0;
    auto alloc = [&](size_t bytes) -> void* {
        void* p = ws + off;
        off = (off + bytes + 255) & ~(size_t)255;
        return p;
    };
    // R3/R5/R7-exact allocation order (gru's measured environment). ybuf and
    // aadj unused but kept so every later buffer keeps its address; aadjt
    // appended at the end.
    u16* hA    = (u16*)alloc(M * 256 * 2);
    u16* hB    = (u16*)alloc(M * 256 * 2);
    u16* msg   = (u16*)alloc(M * 256 * 2);
    u16* ybuf  = (u16*)alloc(M * 768 * 2);
    u16* xpad  = (u16*)alloc(M * 32 * 2);
    float* pa  = (float*)alloc(M * 3 * 4);
    float* pb  = (float*)alloc(M * 3 * 4);
    float* pc  = (float*)alloc(M * 3 * 4);
    u16* wfull = (u16*)alloc(768 * 288 * 2);
    u16* wxn   = (u16*)alloc(256 * 32 * 2);
    u16* convw = (u16*)alloc(196608 * 2);
    u16* w1    = (u16*)alloc(65536 * 2);
    u16* w2    = (u16*)alloc(65536 * 2);
    float* aadj  = (float*)alloc(KNUM * VN * VN * 4);
    float* convb = (float*)alloc(768 * 4);
    float* b1    = (float*)alloc(256 * 4);
    float* b2    = (float*)alloc(256 * 4);
    float* w3    = (float*)alloc(768 * 4);
    float* b3    = (float*)alloc(16);
    u16* aadjt   = (u16*)alloc(2 * 32 * 96 * 2);
    (void)ybuf; (void)aadj;
    if (off > ws_size) return;

    pack_weights<<<512, 256, 0, stream>>>(
        Whr, Whi, Whh, conv_w, W1f, W2f, Af, emul, eadd, Wir, Wii, Win,
        bir, bii, b_in, conv_b, b1f, b2f, W3f, b3f,
        wfull, wxn, convw, w1, w2, aadjt, convb, b1, b2, w3, b3);
    transpose_h<<<NBATCH, 256, 0, stream>>>(hidden, hA);
    init_xpad<<<M_ROWS / 256, 256, 0, stream>>>(inputs, inputs_p, inputs_p2, xpad);
    hipMemcpyAsync(pa, inputs,    M * 3 * 4, hipMemcpyDeviceToDevice, stream);
    hipMemcpyAsync(pb, inputs_p,  M * 3 * 4, hipMemcpyDeviceToDevice, stream);
    hipMemcpyAsync(pc, inputs_p2, M * 3 * 4, hipMemcpyDeviceToDevice, stream);

    u16* hcur = hA;  u16* hnext = hB;
    float* P1 = pa;  float* P2 = pb;  float* P3 = pc;
    const int MB = M_ROWS / 128;  // 832

    for (int s = 0; s < TS; ++s) {
        const u16* m_ptr;
        if (s < 10) {
            // conv gemm + MFMA graph mix fused; y^T panel stays in LDS
            conv_mix<<<NBATCH, 256, 0, stream>>>(hcur, convw, convb, aadjt, msg);
            m_ptr = msg;
        } else {
            m_ptr = hcur;
        }
        gru_fused<<<dim3(MB, 4), 256, 0, stream>>>(m_ptr, xpad, hcur, hnext,
                                                   wfull, wxn);
        // W1+W2+W3+finisher fused: hd/hd2 never touch HBM
        mlp_head<<<M_ROWS / 64, 256, 0, stream>>>(hnext, w1, b1, w2, b2, w3, b3,
                                                  P1, P2, P3, xpad, out, s);
        float* t = P3; P3 = P2; P2 = P1; P1 = t;
        u16* ht = hcur; hcur = hnext; hnext = ht;
    }
}